// Round 10
// baseline (1159.703 us; speedup 1.0000x reference)
//
#include <hip/hip_runtime.h>
#include <hip/hip_bf16.h>
#include <math.h>

#define BATCH 8
#define LRAW 131072
#define L1P 32768
#define L2P 8192
#define SEQ 2048
#define DMODEL 256
#define NHEAD 8
#define DHEAD 32
#define MDIM 128
#define MHALF 64
#define DFF 1024
#define BS_TOK (BATCH*SEQ)
#define INV_SQRT_M 0.08838834764831845f

typedef __attribute__((ext_vector_type(8))) short s8v;   // 8 bf16 (4 VGPRs)
typedef __attribute__((ext_vector_type(4))) float f4v;   // MFMA accumulator

static __device__ __forceinline__ f4v mfma16(s8v a, s8v b, f4v c) {
    return __builtin_amdgcn_mfma_f32_16x16x32_bf16(a, b, c, 0, 0, 0);
}
static __device__ __forceinline__ unsigned short f2bf(float x) {
    __hip_bfloat16 h = __float2bfloat16(x);
    return *reinterpret_cast<unsigned short*>(&h);
}
static __device__ __forceinline__ float bf2f(unsigned short u) {
    __hip_bfloat16 h; *reinterpret_cast<unsigned short*>(&h) = u;
    return __bfloat162float(h);
}
static __device__ __forceinline__ void split8(const float* v, unsigned short* dh, unsigned short* dl) {
#pragma unroll
    for (int j = 0; j < 8; j++) {
        unsigned short hv = f2bf(v[j]);
        dh[j] = hv;
        dl[j] = f2bf(v[j] - bf2f(hv));
    }
}

// ================= conv stem (PASSED, verbatim) =================

__global__ __launch_bounds__(256) void conv0_kernel(const float* __restrict__ x,
    const float* __restrict__ w, const float* __restrict__ bias, float* __restrict__ out)
{
    int idx = blockIdx.x * 256 + threadIdx.x;
    if (idx >= BATCH * L1P) return;
    int b = idx >> 15;
    int p = idx & (L1P - 1);
    const float* xb = x + (size_t)b * LRAW;
    float acc[8];
#pragma unroll
    for (int c = 0; c < 8; c++) acc[c] = 0.f;
#pragma unroll
    for (int i = 0; i < 4; i++) {
        int base = 4 * p + i - 5;
        float y[8];
#pragma unroll
        for (int c = 0; c < 8; c++) y[c] = bias[c];
#pragma unroll
        for (int kk = 0; kk < 11; kk++) {
            int xi = base + kk;
            float xv = (xi >= 0 && xi < LRAW) ? xb[xi] : 0.f;
#pragma unroll
            for (int c = 0; c < 8; c++) y[c] = fmaf(xv, w[kk * 8 + c], y[c]);
        }
#pragma unroll
        for (int c = 0; c < 8; c++) acc[c] += fmaxf(y[c], 0.f);
    }
    float* op = out + (size_t)idx * 8;
#pragma unroll
    for (int c = 0; c < 8; c++) op[c] = acc[c] * 0.25f;
}

__global__ __launch_bounds__(256) void conv1_kernel(const float* __restrict__ in,
    const float* __restrict__ w, const float* __restrict__ bias, float* __restrict__ out)
{
    int idx = blockIdx.x * 256 + threadIdx.x;
    if (idx >= BATCH * L2P) return;
    int b = idx >> 13;
    int p = idx & (L2P - 1);
    const float* ib = in + (size_t)b * L1P * 8;
    float acc[16];
#pragma unroll
    for (int c = 0; c < 16; c++) acc[c] = 0.f;
#pragma unroll
    for (int i = 0; i < 4; i++) {
        float y[16];
#pragma unroll
        for (int c = 0; c < 16; c++) y[c] = bias[c];
#pragma unroll
        for (int kk = 0; kk < 3; kk++) {
            int pos = 4 * p + i + kk - 1;
            if (pos < 0 || pos >= L1P) continue;
            const float* row = ib + (size_t)pos * 8;
#pragma unroll
            for (int ci = 0; ci < 8; ci++) {
                float xv = row[ci];
#pragma unroll
                for (int c = 0; c < 16; c++) y[c] = fmaf(xv, w[(kk * 8 + ci) * 16 + c], y[c]);
            }
        }
#pragma unroll
        for (int c = 0; c < 16; c++) acc[c] += fmaxf(y[c], 0.f);
    }
    float* op = out + (size_t)idx * 16;
#pragma unroll
    for (int c = 0; c < 16; c++) op[c] = acc[c] * 0.25f;
}

__global__ __launch_bounds__(256) void conv2_kernel(const float* __restrict__ in,
    const float* __restrict__ w, const float* __restrict__ bias, float* __restrict__ out)
{
    int bp = blockIdx.x;
    int b = bp / SEQ, p = bp % SEQ;
    int co = threadIdx.x;
    __shared__ float win[6][16];
    int t = threadIdx.x;
    if (t < 96) {
        int r = t / 16, ci = t % 16;
        int pos = 4 * p - 1 + r;
        win[r][ci] = (pos >= 0 && pos < L2P) ? in[((size_t)b * L2P + pos) * 16 + ci] : 0.f;
    }
    __syncthreads();
    float y[4];
#pragma unroll
    for (int i = 0; i < 4; i++) y[i] = bias[co];
#pragma unroll
    for (int kk = 0; kk < 3; kk++) {
#pragma unroll
        for (int ci = 0; ci < 16; ci++) {
            float wv = w[(kk * 16 + ci) * 256 + co];
#pragma unroll
            for (int i = 0; i < 4; i++) y[i] = fmaf(win[i + kk][ci], wv, y[i]);
        }
    }
    float acc = 0.f;
#pragma unroll
    for (int i = 0; i < 4; i++) acc += fmaxf(y[i], 0.f);
    out[((size_t)b * SEQ + p) * 256 + co] = acc * 0.25f;
}

// ================= batched weight transpose+split =================

// four 256x256 transposes in one dispatch; dst = base + z*131072
__global__ __launch_bounds__(256) void tconv4_kernel(
    const float* __restrict__ s0, const float* __restrict__ s1,
    const float* __restrict__ s2, const float* __restrict__ s3,
    unsigned short* __restrict__ dst)
{
    int z = blockIdx.z;
    const float* in = (z == 0) ? s0 : (z == 1) ? s1 : (z == 2) ? s2 : s3;
    unsigned short* outs = dst + (size_t)z * 131072;
    const int R = 256, C = 256;
    __shared__ float tile[32][33];
    int t = threadIdx.x;
    int r0 = blockIdx.y * 32, c0 = blockIdx.x * 32;
    int r = t >> 3, cq = t & 7;
    float4 v = *(const float4*)(in + (size_t)(r0 + r) * C + c0 + cq * 4);
    tile[r][cq * 4 + 0] = v.x; tile[r][cq * 4 + 1] = v.y;
    tile[r][cq * 4 + 2] = v.z; tile[r][cq * 4 + 3] = v.w;
    __syncthreads();
    ushort4 hi, lo;
    unsigned short* hp = (unsigned short*)&hi;
    unsigned short* lp = (unsigned short*)&lo;
#pragma unroll
    for (int j = 0; j < 4; j++) {
        float x = tile[cq * 4 + j][r];
        hp[j] = f2bf(x);
        lp[j] = f2bf(x - bf2f(hp[j]));
    }
    size_t ob = (size_t)(c0 + r) * (2 * R) + r0 + cq * 4;
    *(ushort4*)&outs[ob] = hi;
    *(ushort4*)&outs[ob + R] = lo;
}

// W1 [256x1024] and W2 [1024x256] in one dispatch (z=1 swaps block coords)
__global__ __launch_bounds__(256) void tconv_ff_kernel(
    const float* __restrict__ W1_l, const float* __restrict__ W2_l,
    unsigned short* __restrict__ w1t, unsigned short* __restrict__ w2t)
{
    int z = blockIdx.z;
    int bx = z ? blockIdx.y : blockIdx.x;
    int by = z ? blockIdx.x : blockIdx.y;
    const float* in = z ? W2_l : W1_l;
    unsigned short* outs = z ? w2t : w1t;
    int R = z ? 1024 : 256;
    int C = z ? 256 : 1024;
    __shared__ float tile[32][33];
    int t = threadIdx.x;
    int r0 = by * 32, c0 = bx * 32;
    int r = t >> 3, cq = t & 7;
    float4 v = *(const float4*)(in + (size_t)(r0 + r) * C + c0 + cq * 4);
    tile[r][cq * 4 + 0] = v.x; tile[r][cq * 4 + 1] = v.y;
    tile[r][cq * 4 + 2] = v.z; tile[r][cq * 4 + 3] = v.w;
    __syncthreads();
    ushort4 hi, lo;
    unsigned short* hp = (unsigned short*)&hi;
    unsigned short* lp = (unsigned short*)&lo;
#pragma unroll
    for (int j = 0; j < 4; j++) {
        float x = tile[cq * 4 + j][r];
        hp[j] = f2bf(x);
        lp[j] = f2bf(x - bf2f(hp[j]));
    }
    size_t ob = (size_t)(c0 + r) * (2 * R) + r0 + cq * 4;
    *(ushort4*)&outs[ob] = hi;
    *(ushort4*)&outs[ob + R] = lo;
}

// ================= split-bf16 MFMA GEMMs =================

// generic 64x64, pre-split A/B, f32 out + bias [+resid]  [PASSED, verbatim]
template<bool RESID>
__global__ __launch_bounds__(256) void gemm64s(
    const unsigned short* __restrict__ Abuf, int ARS, int ALO,
    const unsigned short* __restrict__ Bbuf, int BRS, int BLO,
    const float* __restrict__ bias, const float* __restrict__ resid,
    float* __restrict__ C, int N, int K)
{
    __shared__ unsigned short AsH[64 * 32];
    __shared__ unsigned short AsL[64 * 32];
    __shared__ unsigned short BsH[64 * 32];
    __shared__ unsigned short BsL[64 * 32];
    const int t = threadIdx.x;
    const int n0 = blockIdx.x * 64, m0 = blockIdx.y * 64;
    const int row = t >> 2, seg = (t & 3) * 8;
    const int lane = t & 63, w = t >> 6;
    const int wm = w & 1, wn = w >> 1, m16 = lane & 15, q = lane >> 4;
    const f4v fz = {0.f, 0.f, 0.f, 0.f};
    f4v acc[2][2] = {{fz, fz}, {fz, fz}};
    const size_t aoff = (size_t)(m0 + row) * ARS + seg;
    const size_t boff = (size_t)(n0 + row) * BRS + seg;
    const int lw = row * 32 + seg;
    for (int k0 = 0; k0 < K; k0 += 32) {
        __syncthreads();
        *(uint4*)&AsH[lw] = *(const uint4*)(Abuf + aoff + k0);
        *(uint4*)&AsL[lw] = *(const uint4*)(Abuf + aoff + ALO + k0);
        *(uint4*)&BsH[lw] = *(const uint4*)(Bbuf + boff + k0);
        *(uint4*)&BsL[lw] = *(const uint4*)(Bbuf + boff + BLO + k0);
        __syncthreads();
        s8v ah[2], al[2], bh[2], bl[2];
#pragma unroll
        for (int i = 0; i < 2; i++) {
            int ro = (wm * 32 + i * 16 + m16) * 32 + q * 8;
            int co = (wn * 32 + i * 16 + m16) * 32 + q * 8;
            ah[i] = *(const s8v*)&AsH[ro];
            al[i] = *(const s8v*)&AsL[ro];
            bh[i] = *(const s8v*)&BsH[co];
            bl[i] = *(const s8v*)&BsL[co];
        }
#pragma unroll
        for (int mt = 0; mt < 2; mt++)
#pragma unroll
            for (int nt = 0; nt < 2; nt++) {
                acc[mt][nt] = mfma16(ah[mt], bh[nt], acc[mt][nt]);
                acc[mt][nt] = mfma16(ah[mt], bl[nt], acc[mt][nt]);
                acc[mt][nt] = mfma16(al[mt], bh[nt], acc[mt][nt]);
            }
    }
#pragma unroll
    for (int mt = 0; mt < 2; mt++)
#pragma unroll
        for (int nt = 0; nt < 2; nt++)
#pragma unroll
            for (int r = 0; r < 4; r++) {
                int rg = m0 + wm * 32 + mt * 16 + q * 4 + r;
                int cg = n0 + wn * 32 + nt * 16 + m16;
                float val = acc[mt][nt][r] + bias[cg];
                if (RESID) val += resid[(size_t)rg * N + cg];
                C[(size_t)rg * N + cg] = val;
            }
}

// fused QKV: inline row-mean + center + split A; B = concat wqkv [768][512]
__global__ __launch_bounds__(256) void gemm64_qkv(
    const float* __restrict__ hc, const unsigned short* __restrict__ Bbuf,
    const float* __restrict__ bk, const float* __restrict__ bv, const float* __restrict__ bq,
    float* __restrict__ C)
{
    __shared__ unsigned short AsH[64 * 32];
    __shared__ unsigned short AsL[64 * 32];
    __shared__ unsigned short BsH[64 * 32];
    __shared__ unsigned short BsL[64 * 32];
    __shared__ float psum[64][4];
    __shared__ float muS[64];
    const int t = threadIdx.x;
    const int n0 = blockIdx.x * 64, m0 = blockIdx.y * 64;
    const int row = t >> 2, q4 = t & 3, seg = q4 * 8;
    const int lane = t & 63, w = t >> 6;
    const int wm = w & 1, wn = w >> 1, m16 = lane & 15, q = lane >> 4;
    // row mean: 4 threads per row, 64 cols each
    {
        const float* rp = hc + (size_t)(m0 + row) * DMODEL + q4 * 64;
        float s = 0.f;
#pragma unroll
        for (int j = 0; j < 64; j += 4) {
            float4 xv = *(const float4*)(rp + j);
            s += xv.x + xv.y + xv.z + xv.w;
        }
        psum[row][q4] = s;
    }
    __syncthreads();
    if (t < 64) muS[t] = (psum[t][0] + psum[t][1] + psum[t][2] + psum[t][3]) * (1.0f / 256.0f);
    const f4v fz = {0.f, 0.f, 0.f, 0.f};
    f4v acc[2][2] = {{fz, fz}, {fz, fz}};
    const float* ap = hc + (size_t)(m0 + row) * DMODEL + seg;
    const size_t boff = (size_t)(n0 + row) * 512 + seg;
    const int lw = row * 32 + seg;
    for (int k0 = 0; k0 < 256; k0 += 32) {
        __syncthreads();
        {
            float mu = muS[row];
            float4 a0 = *(const float4*)(ap + k0);
            float4 a1 = *(const float4*)(ap + k0 + 4);
            float v[8] = {a0.x - mu, a0.y - mu, a0.z - mu, a0.w - mu,
                          a1.x - mu, a1.y - mu, a1.z - mu, a1.w - mu};
            split8(v, &AsH[lw], &AsL[lw]);
        }
        *(uint4*)&BsH[lw] = *(const uint4*)(Bbuf + boff + k0);
        *(uint4*)&BsL[lw] = *(const uint4*)(Bbuf + boff + 256 + k0);
        __syncthreads();
        s8v ah[2], al[2], bh[2], bl[2];
#pragma unroll
        for (int i = 0; i < 2; i++) {
            int ro = (wm * 32 + i * 16 + m16) * 32 + q * 8;
            int co = (wn * 32 + i * 16 + m16) * 32 + q * 8;
            ah[i] = *(const s8v*)&AsH[ro];
            al[i] = *(const s8v*)&AsL[ro];
            bh[i] = *(const s8v*)&BsH[co];
            bl[i] = *(const s8v*)&BsL[co];
        }
#pragma unroll
        for (int mt = 0; mt < 2; mt++)
#pragma unroll
            for (int nt = 0; nt < 2; nt++) {
                acc[mt][nt] = mfma16(ah[mt], bh[nt], acc[mt][nt]);
                acc[mt][nt] = mfma16(ah[mt], bl[nt], acc[mt][nt]);
                acc[mt][nt] = mfma16(al[mt], bh[nt], acc[mt][nt]);
            }
    }
    const float* bp = (n0 < 256) ? bk : (n0 < 512) ? (bv - 256) : (bq - 512);
#pragma unroll
    for (int mt = 0; mt < 2; mt++)
#pragma unroll
        for (int nt = 0; nt < 2; nt++)
#pragma unroll
            for (int r = 0; r < 4; r++) {
                int rg = m0 + wm * 32 + mt * 16 + q * 4 + r;
                int cg = n0 + wn * 32 + nt * 16 + m16;
                C[(size_t)rg * 768 + cg] = acc[mt][nt][r] + bp[cg];
            }
}

// FF1: inline row-mean + center + split A; relu + split out
__global__ __launch_bounds__(256) void gemm128_ff1(
    const float* __restrict__ hc, const unsigned short* __restrict__ Bbuf,
    const float* __restrict__ bias, unsigned short* __restrict__ Us)
{
    __shared__ unsigned short AsH[128 * 32];
    __shared__ unsigned short AsL[128 * 32];
    __shared__ unsigned short BsH[128 * 32];
    __shared__ unsigned short BsL[128 * 32];
    __shared__ float psum[128][2];
    __shared__ float muS[128];
    const int t = threadIdx.x;
    const int n0 = blockIdx.x * 128, m0 = blockIdx.y * 128;
    const int lane = t & 63, w = t >> 6;
    const int wm = w & 1, wn = w >> 1, m16 = lane & 15, q = lane >> 4;
    // row mean: 2 threads per row, 128 cols each
    {
        int r = t >> 1, hcf = t & 1;
        const float* rp = hc + (size_t)(m0 + r) * DMODEL + hcf * 128;
        float s = 0.f;
#pragma unroll
        for (int j = 0; j < 128; j += 4) {
            float4 xv = *(const float4*)(rp + j);
            s += xv.x + xv.y + xv.z + xv.w;
        }
        psum[r][hcf] = s;
    }
    __syncthreads();
    if (t < 128) muS[t] = (psum[t][0] + psum[t][1]) * (1.0f / 256.0f);
    const f4v fz = {0.f, 0.f, 0.f, 0.f};
    f4v acc[4][4];
#pragma unroll
    for (int i = 0; i < 4; i++)
#pragma unroll
        for (int j = 0; j < 4; j++) acc[i][j] = fz;
    const int c0 = t * 2, c1 = t * 2 + 1;
    const int r0i = c0 >> 2, s0i = (c0 & 3) * 8;
    const int r1i = c1 >> 2, s1i = (c1 & 3) * 8;
    const float* ap0 = hc + (size_t)(m0 + r0i) * DMODEL + s0i;
    const float* ap1 = hc + (size_t)(m0 + r1i) * DMODEL + s1i;
    const size_t b0o = (size_t)(n0 + r0i) * 512 + s0i;
    const size_t b1o = (size_t)(n0 + r1i) * 512 + s1i;
    for (int k0 = 0; k0 < 256; k0 += 32) {
        __syncthreads();
        {
            float mu0 = muS[r0i];
            float4 a0 = *(const float4*)(ap0 + k0);
            float4 a1 = *(const float4*)(ap0 + k0 + 4);
            float v[8] = {a0.x - mu0, a0.y - mu0, a0.z - mu0, a0.w - mu0,
                          a1.x - mu0, a1.y - mu0, a1.z - mu0, a1.w - mu0};
            split8(v, &AsH[r0i * 32 + s0i], &AsL[r0i * 32 + s0i]);
        }
        {
            float mu1 = muS[r1i];
            float4 a0 = *(const float4*)(ap1 + k0);
            float4 a1 = *(const float4*)(ap1 + k0 + 4);
            float v[8] = {a0.x - mu1, a0.y - mu1, a0.z - mu1, a0.w - mu1,
                          a1.x - mu1, a1.y - mu1, a1.z - mu1, a1.w - mu1};
            split8(v, &AsH[r1i * 32 + s1i], &AsL[r1i * 32 + s1i]);
        }
        *(uint4*)&BsH[r0i * 32 + s0i] = *(const uint4*)(Bbuf + b0o + k0);
        *(uint4*)&BsH[r1i * 32 + s1i] = *(const uint4*)(Bbuf + b1o + k0);
        *(uint4*)&BsL[r0i * 32 + s0i] = *(const uint4*)(Bbuf + b0o + 256 + k0);
        *(uint4*)&BsL[r1i * 32 + s1i] = *(const uint4*)(Bbuf + b1o + 256 + k0);
        __syncthreads();
        s8v ah[4], al[4], bh[4], bl[4];
#pragma unroll
        for (int i = 0; i < 4; i++) {
            int ro = (wm * 64 + i * 16 + m16) * 32 + q * 8;
            int co = (wn * 64 + i * 16 + m16) * 32 + q * 8;
            ah[i] = *(const s8v*)&AsH[ro];
            al[i] = *(const s8v*)&AsL[ro];
            bh[i] = *(const s8v*)&BsH[co];
            bl[i] = *(const s8v*)&BsL[co];
        }
#pragma unroll
        for (int mt = 0; mt < 4; mt++)
#pragma unroll
            for (int nt = 0; nt < 4; nt++) {
                acc[mt][nt] = mfma16(ah[mt], bh[nt], acc[mt][nt]);
                acc[mt][nt] = mfma16(ah[mt], bl[nt], acc[mt][nt]);
                acc[mt][nt] = mfma16(al[mt], bh[nt], acc[mt][nt]);
            }
    }
#pragma unroll
    for (int mt = 0; mt < 4; mt++)
#pragma unroll
        for (int nt = 0; nt < 4; nt++)
#pragma unroll
            for (int r = 0; r < 4; r++) {
                int rg = m0 + wm * 64 + mt * 16 + q * 4 + r;
                int cg = n0 + wn * 64 + nt * 16 + m16;
                float val = fmaxf(acc[mt][nt][r] + bias[cg], 0.f);
                unsigned short hv = f2bf(val);
                Us[(size_t)rg * 2048 + cg] = hv;
                Us[(size_t)rg * 2048 + 1024 + cg] = f2bf(val - bf2f(hv));
            }
}

// ================= lean phi kernels =================

// 256 blocks (16 bh x 16 sub), 128 tokens, BOTH halves (proj computed once)
__global__ __launch_bounds__(256) void phi_kv_chunk(
    const float* __restrict__ qkv, const float* __restrict__ om_l,
    const float* __restrict__ g_l, float* __restrict__ part)
{
    int bx = blockIdx.x;
    int sub = bx & 15;
    int bh = bx >> 4;
    int b_local = bh >> 3, h = bh & 7;
    int t = threadIdx.x;
    __shared__ float omS[32][64];
    __shared__ float kS[8][32];
    __shared__ float vS[8][32];
    __shared__ float ktS[8][128];
    for (int i = t; i < 2048; i += 256) omS[i >> 6][i & 63] = om_l[(size_t)h * 2048 + i];
    float g = g_l[h];
    int e = t & 31;
    int ms = t >> 5;
    float accv[16];
#pragma unroll
    for (int i = 0; i < 16; i++) accv[i] = 0.f;
    int row0 = b_local * 2048 + sub * 128;
    for (int i0 = 0; i0 < 128; i0 += 8) {
        __syncthreads();
        {
            int row = row0 + i0 + ms;
            kS[ms][e] = qkv[(size_t)row * 768 + h * 32 + e];
            vS[ms][e] = qkv[(size_t)row * 768 + 256 + h * 32 + e];
        }
        __syncthreads();
        {
            int id = t * 2;
            int t2 = id >> 6;
            int mp = id & 63;
            float t_s = (float)(sub * 128 + i0 + t2) * (1.0f / 2047.0f);
#pragma unroll
            for (int u2 = 0; u2 < 2; u2++) {
                int mpp = mp + u2;
                float proj = 0.f;
#pragma unroll
                for (int d = 0; d < 32; d++) proj = fmaf(kS[t2][d], omS[d][mpp], proj);
                float slope = 2.0f - (float)mpp * 0.03125f;
                ktS[t2][mpp]      = __cosf(proj) * (INV_SQRT_M * __expf(-g * t_s * slope));
                ktS[t2][64 + mpp] = __sinf(proj) * (INV_SQRT_M * __expf(-g * (1.0f - t_s) * slope));
            }
        }
        __syncthreads();
#pragma unroll
        for (int tok = 0; tok < 8; tok++) {
            float vv = vS[tok][e];
#pragma unroll
            for (int j = 0; j < 16; j++)
                accv[j] = fmaf(ktS[tok][ms * 16 + j], vv, accv[j]);
        }
    }
    float* pp = part + (size_t)(bh * 16 + sub) * 4096;
#pragma unroll
    for (int j = 0; j < 16; j++) pp[(ms * 16 + j) * 32 + e] = accv[j];
}

// 256 blocks (16 bh x 16 sub); reduces its bh's 16 partials inline into kvS
__global__ __launch_bounds__(256) void phi_o_chunk(
    const float* __restrict__ qkv, const float* __restrict__ part,
    const float* __restrict__ om_l, const float* __restrict__ g_l,
    unsigned short* __restrict__ osplit)
{
    int bx = blockIdx.x;
    int sub = bx & 15;
    int bh = bx >> 4;
    int b_local = bh >> 3, h = bh & 7;
    int t = threadIdx.x;
    __shared__ float omS[32][64];
    __shared__ float kvS[128][32];
    __shared__ float qS[8][32];
    __shared__ float qtS[8][128];
    for (int i = t; i < 2048; i += 256) omS[i >> 6][i & 63] = om_l[(size_t)h * 2048 + i];
    {
        const float* base = part + (size_t)(bh * 16) * 4096;
        for (int i = t; i < 4096; i += 256) {
            float s = 0.f;
#pragma unroll
            for (int sb = 0; sb < 16; sb++) s += base[(size_t)sb * 4096 + i];
            kvS[i >> 5][i & 31] = s;
        }
    }
    float g = g_l[h];
    int e = t & 31, tsx = t >> 5;
    int row0 = b_local * 2048 + sub * 128;
    for (int i0 = 0; i0 < 128; i0 += 8) {
        __syncthreads();
        qS[tsx][e] = qkv[(size_t)(row0 + i0 + tsx) * 768 + 512 + h * 32 + e];
        __syncthreads();
        {
            int id = t * 2, t2 = id >> 6, mp = id & 63;
            float t_s = (float)(sub * 128 + i0 + t2) * (1.0f / 2047.0f);
#pragma unroll
            for (int u2 = 0; u2 < 2; u2++) {
                int mpp = mp + u2;
                float proj = 0.f;
#pragma unroll
                for (int d = 0; d < 32; d++) proj = fmaf(qS[t2][d], omS[d][mpp], proj);
                float slope = 2.0f - (float)mpp * 0.03125f;
                qtS[t2][mpp]      = __cosf(proj) * (INV_SQRT_M * __expf(g * t_s * slope));
                qtS[t2][64 + mpp] = __sinf(proj) * (INV_SQRT_M * __expf(g * (1.0f - t_s) * slope));
            }
        }
        __syncthreads();
        {
            float ov = 0.f;
#pragma unroll
            for (int m = 0; m < 128; m++) ov = fmaf(qtS[tsx][m], kvS[m][e], ov);
            size_t row = (size_t)(row0 + i0 + tsx);
            unsigned short hv = f2bf(ov);
            osplit[row * 512 + h * 32 + e] = hv;
            osplit[row * 512 + 256 + h * 32 + e] = f2bf(ov - bf2f(hv));
        }
    }
}

__global__ __launch_bounds__(256) void copy_kernel(const float4* __restrict__ src,
    float4* __restrict__ dst)
{
    int i = blockIdx.x * 1024 + threadIdx.x * 4;
#pragma unroll
    for (int j = 0; j < 4; j++) dst[i + j] = src[i + j];
}

// ================= host =================

extern "C" void kernel_launch(void* const* d_in, const int* in_sizes, int n_in,
                              void* d_out, int out_size, void* d_ws, size_t ws_size,
                              hipStream_t stream)
{
    (void)in_sizes; (void)n_in; (void)out_size; (void)ws_size;
    const float* x    = (const float*)d_in[0];
    const float* cw0  = (const float*)d_in[1];
    const float* cb0  = (const float*)d_in[2];
    const float* cw1  = (const float*)d_in[3];
    const float* cb1  = (const float*)d_in[4];
    const float* cw2  = (const float*)d_in[5];
    const float* cb2  = (const float*)d_in[6];
    const float* Wq   = (const float*)d_in[7];
    const float* bq   = (const float*)d_in[8];
    const float* Wk   = (const float*)d_in[9];
    const float* bk   = (const float*)d_in[10];
    const float* Wv   = (const float*)d_in[11];
    const float* bv   = (const float*)d_in[12];
    const float* Wo   = (const float*)d_in[13];
    const float* bo   = (const float*)d_in[14];
    const float* omega= (const float*)d_in[15];
    const float* gamma= (const float*)d_in[16];
    const float* W1   = (const float*)d_in[17];
    const float* b1   = (const float*)d_in[18];
    const float* W2   = (const float*)d_in[19];
    const float* b2   = (const float*)d_in[20];

    // ws layout (21 MiB total; 24 MiB proven):
    //   hc [0,16M) | part [16,20M) (w1t/w2t in FF phase) | wqkvt+wot [20M,21M)
    char* wsb = (char*)d_ws;
    float* hc     = (float*)wsb;
    float* part   = (float*)(wsb + ((size_t)16 << 20));
    unsigned short* w1t = (unsigned short*)part;
    unsigned short* w2t = (unsigned short*)part + 524288;          // +1 MiB
    unsigned short* wqkvt = (unsigned short*)(wsb + ((size_t)20 << 20));
    unsigned short* wot   = wqkvt + 3 * 131072;                    // z=3 slot

    // d_out (16 MiB) scratch:
    //   stem: h0 [0,8M) | h1 [8,12M)
    //   attn: qkvc f32 [0,12M) (4096 x 768) | osplit [12,16M)
    //   FF:   usp [0,16M)
    char* dob = (char*)d_out;
    float* h0 = (float*)dob;
    float* h1 = (float*)(dob + ((size_t)8 << 20));
    float* qkvc = (float*)dob;
    unsigned short* osplit = (unsigned short*)(dob + ((size_t)12 << 20));
    unsigned short* usp    = (unsigned short*)dob;

    conv0_kernel<<<(BATCH * L1P + 255) / 256, 256, 0, stream>>>(x, cw0, cb0, h0);
    conv1_kernel<<<(BATCH * L2P + 255) / 256, 256, 0, stream>>>(h0, cw1, cb1, h1);
    conv2_kernel<<<BATCH * SEQ, 256, 0, stream>>>(h1, cw2, cb2, hc);

    const int CH = 4096;   // attention chunk rows (2 sequences)
    const int MQ = 4096;   // FF chunk rows

    for (int l = 0; l < 2; l++) {
        const float* Wq_l = Wq + (size_t)l * DMODEL * DMODEL;
        const float* bq_l = bq + (size_t)l * DMODEL;
        const float* Wk_l = Wk + (size_t)l * DMODEL * DMODEL;
        const float* bk_l = bk + (size_t)l * DMODEL;
        const float* Wv_l = Wv + (size_t)l * DMODEL * DMODEL;
        const float* bv_l = bv + (size_t)l * DMODEL;
        const float* Wo_l = Wo + (size_t)l * DMODEL * DMODEL;
        const float* bo_l = bo + (size_t)l * DMODEL;
        const float* om_l = omega + (size_t)l * NHEAD * DHEAD * MHALF;
        const float* g_l  = gamma + (size_t)l * NHEAD;
        const float* W1_l = W1 + (size_t)l * DMODEL * DFF;
        const float* b1_l = b1 + (size_t)l * DFF;
        const float* W2_l = W2 + (size_t)l * DFF * DMODEL;
        const float* b2_l = b2 + (size_t)l * DMODEL;

        // attention: one batched transpose (k,v,q,o slots)
        tconv4_kernel<<<dim3(8, 8, 4), 256, 0, stream>>>(Wk_l, Wv_l, Wq_l, Wo_l, wqkvt);

        for (int c = 0; c < BS_TOK / CH; c++) {
            size_t ro = (size_t)c * CH * DMODEL;
            gemm64_qkv<<<dim3(12, CH / 64), 256, 0, stream>>>(
                hc + ro, wqkvt, bk_l, bv_l, bq_l, qkvc);
            phi_kv_chunk<<<256, 256, 0, stream>>>(qkvc, om_l, g_l, part);
            phi_o_chunk<<<256, 256, 0, stream>>>(qkvc, part, om_l, g_l, osplit);
            gemm64s<true><<<dim3(4, CH / 64), 256, 0, stream>>>(
                osplit, 512, 256, wot, 512, 256, bo_l, hc + ro, hc + ro, DMODEL, DMODEL);
        }

        // FF: one batched transpose (W1 + W2)
        tconv_ff_kernel<<<dim3(32, 8, 2), 256, 0, stream>>>(W1_l, W2_l, w1t, w2t);
        for (int c = 0; c < BS_TOK / MQ; c++) {
            size_t ro = (size_t)c * MQ * DMODEL;
            gemm128_ff1<<<dim3(DFF / 128, MQ / 128), 256, 0, stream>>>(
                hc + ro, w1t, b1_l, usp);
            gemm64s<true><<<dim3(DMODEL / 64, MQ / 64), 256, 0, stream>>>(
                usp, 2048, 1024, w2t, 2048, 1024, b2_l, hc + ro, hc + ro, DMODEL, DFF);
        }
    }

    copy_kernel<<<(BS_TOK * DMODEL / 4) / 1024, 256, 0, stream>>>(
        (const float4*)hc, (float4*)d_out);
}

// Round 11
// 768.739 us; speedup vs baseline: 1.5086x; 1.5086x over previous
//
#include <hip/hip_runtime.h>
#include <hip/hip_bf16.h>
#include <math.h>

#define BATCH 8
#define LRAW 131072
#define L1P 32768
#define L2P 8192
#define SEQ 2048
#define DMODEL 256
#define NHEAD 8
#define DHEAD 32
#define MDIM 128
#define MHALF 64
#define DFF 1024
#define BS_TOK (BATCH*SEQ)
#define INV_SQRT_M 0.08838834764831845f

typedef __attribute__((ext_vector_type(8))) short s8v;   // 8 bf16 (4 VGPRs)
typedef __attribute__((ext_vector_type(4))) float f4v;   // MFMA accumulator

static __device__ __forceinline__ f4v mfma16(s8v a, s8v b, f4v c) {
    return __builtin_amdgcn_mfma_f32_16x16x32_bf16(a, b, c, 0, 0, 0);
}
static __device__ __forceinline__ unsigned short f2bf(float x) {
    __hip_bfloat16 h = __float2bfloat16(x);
    return *reinterpret_cast<unsigned short*>(&h);
}
static __device__ __forceinline__ float bf2f(unsigned short u) {
    __hip_bfloat16 h; *reinterpret_cast<unsigned short*>(&h) = u;
    return __bfloat162float(h);
}
static __device__ __forceinline__ void split8(const float* v, unsigned short* dh, unsigned short* dl) {
#pragma unroll
    for (int j = 0; j < 8; j++) {
        unsigned short hv = f2bf(v[j]);
        dh[j] = hv;
        dl[j] = f2bf(v[j] - bf2f(hv));
    }
}

// ================= conv stem (PASSED, verbatim) =================

__global__ __launch_bounds__(256) void conv0_kernel(const float* __restrict__ x,
    const float* __restrict__ w, const float* __restrict__ bias, float* __restrict__ out)
{
    int idx = blockIdx.x * 256 + threadIdx.x;
    if (idx >= BATCH * L1P) return;
    int b = idx >> 15;
    int p = idx & (L1P - 1);
    const float* xb = x + (size_t)b * LRAW;
    float acc[8];
#pragma unroll
    for (int c = 0; c < 8; c++) acc[c] = 0.f;
#pragma unroll
    for (int i = 0; i < 4; i++) {
        int base = 4 * p + i - 5;
        float y[8];
#pragma unroll
        for (int c = 0; c < 8; c++) y[c] = bias[c];
#pragma unroll
        for (int kk = 0; kk < 11; kk++) {
            int xi = base + kk;
            float xv = (xi >= 0 && xi < LRAW) ? xb[xi] : 0.f;
#pragma unroll
            for (int c = 0; c < 8; c++) y[c] = fmaf(xv, w[kk * 8 + c], y[c]);
        }
#pragma unroll
        for (int c = 0; c < 8; c++) acc[c] += fmaxf(y[c], 0.f);
    }
    float* op = out + (size_t)idx * 8;
#pragma unroll
    for (int c = 0; c < 8; c++) op[c] = acc[c] * 0.25f;
}

__global__ __launch_bounds__(256) void conv1_kernel(const float* __restrict__ in,
    const float* __restrict__ w, const float* __restrict__ bias, float* __restrict__ out)
{
    int idx = blockIdx.x * 256 + threadIdx.x;
    if (idx >= BATCH * L2P) return;
    int b = idx >> 13;
    int p = idx & (L2P - 1);
    const float* ib = in + (size_t)b * L1P * 8;
    float acc[16];
#pragma unroll
    for (int c = 0; c < 16; c++) acc[c] = 0.f;
#pragma unroll
    for (int i = 0; i < 4; i++) {
        float y[16];
#pragma unroll
        for (int c = 0; c < 16; c++) y[c] = bias[c];
#pragma unroll
        for (int kk = 0; kk < 3; kk++) {
            int pos = 4 * p + i + kk - 1;
            if (pos < 0 || pos >= L1P) continue;
            const float* row = ib + (size_t)pos * 8;
#pragma unroll
            for (int ci = 0; ci < 8; ci++) {
                float xv = row[ci];
#pragma unroll
                for (int c = 0; c < 16; c++) y[c] = fmaf(xv, w[(kk * 8 + ci) * 16 + c], y[c]);
            }
        }
#pragma unroll
        for (int c = 0; c < 16; c++) acc[c] += fmaxf(y[c], 0.f);
    }
    float* op = out + (size_t)idx * 16;
#pragma unroll
    for (int c = 0; c < 16; c++) op[c] = acc[c] * 0.25f;
}

__global__ __launch_bounds__(256) void conv2_kernel(const float* __restrict__ in,
    const float* __restrict__ w, const float* __restrict__ bias, float* __restrict__ out)
{
    int bp = blockIdx.x;
    int b = bp / SEQ, p = bp % SEQ;
    int co = threadIdx.x;
    __shared__ float win[6][16];
    int t = threadIdx.x;
    if (t < 96) {
        int r = t / 16, ci = t % 16;
        int pos = 4 * p - 1 + r;
        win[r][ci] = (pos >= 0 && pos < L2P) ? in[((size_t)b * L2P + pos) * 16 + ci] : 0.f;
    }
    __syncthreads();
    float y[4];
#pragma unroll
    for (int i = 0; i < 4; i++) y[i] = bias[co];
#pragma unroll
    for (int kk = 0; kk < 3; kk++) {
#pragma unroll
        for (int ci = 0; ci < 16; ci++) {
            float wv = w[(kk * 16 + ci) * 256 + co];
#pragma unroll
            for (int i = 0; i < 4; i++) y[i] = fmaf(win[i + kk][ci], wv, y[i]);
        }
    }
    float acc = 0.f;
#pragma unroll
    for (int i = 0; i < 4; i++) acc += fmaxf(y[i], 0.f);
    out[((size_t)b * SEQ + p) * 256 + co] = acc * 0.25f;
}

// ================= batched weight transpose+split (PASSED r10) =================

__global__ __launch_bounds__(256) void tconv4_kernel(
    const float* __restrict__ s0, const float* __restrict__ s1,
    const float* __restrict__ s2, const float* __restrict__ s3,
    unsigned short* __restrict__ dst)
{
    int z = blockIdx.z;
    const float* in = (z == 0) ? s0 : (z == 1) ? s1 : (z == 2) ? s2 : s3;
    unsigned short* outs = dst + (size_t)z * 131072;
    const int R = 256, C = 256;
    __shared__ float tile[32][33];
    int t = threadIdx.x;
    int r0 = blockIdx.y * 32, c0 = blockIdx.x * 32;
    int r = t >> 3, cq = t & 7;
    float4 v = *(const float4*)(in + (size_t)(r0 + r) * C + c0 + cq * 4);
    tile[r][cq * 4 + 0] = v.x; tile[r][cq * 4 + 1] = v.y;
    tile[r][cq * 4 + 2] = v.z; tile[r][cq * 4 + 3] = v.w;
    __syncthreads();
    ushort4 hi, lo;
    unsigned short* hp = (unsigned short*)&hi;
    unsigned short* lp = (unsigned short*)&lo;
#pragma unroll
    for (int j = 0; j < 4; j++) {
        float x = tile[cq * 4 + j][r];
        hp[j] = f2bf(x);
        lp[j] = f2bf(x - bf2f(hp[j]));
    }
    size_t ob = (size_t)(c0 + r) * (2 * R) + r0 + cq * 4;
    *(ushort4*)&outs[ob] = hi;
    *(ushort4*)&outs[ob + R] = lo;
}

__global__ __launch_bounds__(256) void tconv_ff_kernel(
    const float* __restrict__ W1_l, const float* __restrict__ W2_l,
    unsigned short* __restrict__ w1t, unsigned short* __restrict__ w2t)
{
    int z = blockIdx.z;
    int bx = z ? blockIdx.y : blockIdx.x;
    int by = z ? blockIdx.x : blockIdx.y;
    const float* in = z ? W2_l : W1_l;
    unsigned short* outs = z ? w2t : w1t;
    int R = z ? 1024 : 256;
    int C = z ? 256 : 1024;
    __shared__ float tile[32][33];
    int t = threadIdx.x;
    int r0 = by * 32, c0 = bx * 32;
    int r = t >> 3, cq = t & 7;
    float4 v = *(const float4*)(in + (size_t)(r0 + r) * C + c0 + cq * 4);
    tile[r][cq * 4 + 0] = v.x; tile[r][cq * 4 + 1] = v.y;
    tile[r][cq * 4 + 2] = v.z; tile[r][cq * 4 + 3] = v.w;
    __syncthreads();
    ushort4 hi, lo;
    unsigned short* hp = (unsigned short*)&hi;
    unsigned short* lp = (unsigned short*)&lo;
#pragma unroll
    for (int j = 0; j < 4; j++) {
        float x = tile[cq * 4 + j][r];
        hp[j] = f2bf(x);
        lp[j] = f2bf(x - bf2f(hp[j]));
    }
    size_t ob = (size_t)(c0 + r) * (2 * R) + r0 + cq * 4;
    *(ushort4*)&outs[ob] = hi;
    *(ushort4*)&outs[ob + R] = lo;
}

// ================= split-bf16 MFMA GEMMs (PASSED machinery) =================

template<bool RESID>
__global__ __launch_bounds__(256) void gemm64s(
    const unsigned short* __restrict__ Abuf, int ARS, int ALO,
    const unsigned short* __restrict__ Bbuf, int BRS, int BLO,
    const float* __restrict__ bias, const float* __restrict__ resid,
    float* __restrict__ C, int N, int K)
{
    __shared__ unsigned short AsH[64 * 32];
    __shared__ unsigned short AsL[64 * 32];
    __shared__ unsigned short BsH[64 * 32];
    __shared__ unsigned short BsL[64 * 32];
    const int t = threadIdx.x;
    const int n0 = blockIdx.x * 64, m0 = blockIdx.y * 64;
    const int row = t >> 2, seg = (t & 3) * 8;
    const int lane = t & 63, w = t >> 6;
    const int wm = w & 1, wn = w >> 1, m16 = lane & 15, q = lane >> 4;
    const f4v fz = {0.f, 0.f, 0.f, 0.f};
    f4v acc[2][2] = {{fz, fz}, {fz, fz}};
    const size_t aoff = (size_t)(m0 + row) * ARS + seg;
    const size_t boff = (size_t)(n0 + row) * BRS + seg;
    const int lw = row * 32 + seg;
    for (int k0 = 0; k0 < K; k0 += 32) {
        __syncthreads();
        *(uint4*)&AsH[lw] = *(const uint4*)(Abuf + aoff + k0);
        *(uint4*)&AsL[lw] = *(const uint4*)(Abuf + aoff + ALO + k0);
        *(uint4*)&BsH[lw] = *(const uint4*)(Bbuf + boff + k0);
        *(uint4*)&BsL[lw] = *(const uint4*)(Bbuf + boff + BLO + k0);
        __syncthreads();
        s8v ah[2], al[2], bh[2], bl[2];
#pragma unroll
        for (int i = 0; i < 2; i++) {
            int ro = (wm * 32 + i * 16 + m16) * 32 + q * 8;
            int co = (wn * 32 + i * 16 + m16) * 32 + q * 8;
            ah[i] = *(const s8v*)&AsH[ro];
            al[i] = *(const s8v*)&AsL[ro];
            bh[i] = *(const s8v*)&BsH[co];
            bl[i] = *(const s8v*)&BsL[co];
        }
#pragma unroll
        for (int mt = 0; mt < 2; mt++)
#pragma unroll
            for (int nt = 0; nt < 2; nt++) {
                acc[mt][nt] = mfma16(ah[mt], bh[nt], acc[mt][nt]);
                acc[mt][nt] = mfma16(ah[mt], bl[nt], acc[mt][nt]);
                acc[mt][nt] = mfma16(al[mt], bh[nt], acc[mt][nt]);
            }
    }
#pragma unroll
    for (int mt = 0; mt < 2; mt++)
#pragma unroll
        for (int nt = 0; nt < 2; nt++)
#pragma unroll
            for (int r = 0; r < 4; r++) {
                int rg = m0 + wm * 32 + mt * 16 + q * 4 + r;
                int cg = n0 + wn * 32 + nt * 16 + m16;
                float val = acc[mt][nt][r] + bias[cg];
                if (RESID) val += resid[(size_t)rg * N + cg];
                C[(size_t)rg * N + cg] = val;
            }
}

// fused QKV: inline row-mean + center + split A; B = concat wqkv [768][512]
__global__ __launch_bounds__(256) void gemm64_qkv(
    const float* __restrict__ hc, const unsigned short* __restrict__ Bbuf,
    const float* __restrict__ bk, const float* __restrict__ bv, const float* __restrict__ bq,
    float* __restrict__ C)
{
    __shared__ unsigned short AsH[64 * 32];
    __shared__ unsigned short AsL[64 * 32];
    __shared__ unsigned short BsH[64 * 32];
    __shared__ unsigned short BsL[64 * 32];
    __shared__ float psum[64][4];
    __shared__ float muS[64];
    const int t = threadIdx.x;
    const int n0 = blockIdx.x * 64, m0 = blockIdx.y * 64;
    const int row = t >> 2, q4 = t & 3, seg = q4 * 8;
    const int lane = t & 63, w = t >> 6;
    const int wm = w & 1, wn = w >> 1, m16 = lane & 15, q = lane >> 4;
    {
        const float* rp = hc + (size_t)(m0 + row) * DMODEL + q4 * 64;
        float s = 0.f;
#pragma unroll
        for (int j = 0; j < 64; j += 4) {
            float4 xv = *(const float4*)(rp + j);
            s += xv.x + xv.y + xv.z + xv.w;
        }
        psum[row][q4] = s;
    }
    __syncthreads();
    if (t < 64) muS[t] = (psum[t][0] + psum[t][1] + psum[t][2] + psum[t][3]) * (1.0f / 256.0f);
    const f4v fz = {0.f, 0.f, 0.f, 0.f};
    f4v acc[2][2] = {{fz, fz}, {fz, fz}};
    const float* ap = hc + (size_t)(m0 + row) * DMODEL + seg;
    const size_t boff = (size_t)(n0 + row) * 512 + seg;
    const int lw = row * 32 + seg;
    for (int k0 = 0; k0 < 256; k0 += 32) {
        __syncthreads();
        {
            float mu = muS[row];
            float4 a0 = *(const float4*)(ap + k0);
            float4 a1 = *(const float4*)(ap + k0 + 4);
            float v[8] = {a0.x - mu, a0.y - mu, a0.z - mu, a0.w - mu,
                          a1.x - mu, a1.y - mu, a1.z - mu, a1.w - mu};
            split8(v, &AsH[lw], &AsL[lw]);
        }
        *(uint4*)&BsH[lw] = *(const uint4*)(Bbuf + boff + k0);
        *(uint4*)&BsL[lw] = *(const uint4*)(Bbuf + boff + 256 + k0);
        __syncthreads();
        s8v ah[2], al[2], bh[2], bl[2];
#pragma unroll
        for (int i = 0; i < 2; i++) {
            int ro = (wm * 32 + i * 16 + m16) * 32 + q * 8;
            int co = (wn * 32 + i * 16 + m16) * 32 + q * 8;
            ah[i] = *(const s8v*)&AsH[ro];
            al[i] = *(const s8v*)&AsL[ro];
            bh[i] = *(const s8v*)&BsH[co];
            bl[i] = *(const s8v*)&BsL[co];
        }
#pragma unroll
        for (int mt = 0; mt < 2; mt++)
#pragma unroll
            for (int nt = 0; nt < 2; nt++) {
                acc[mt][nt] = mfma16(ah[mt], bh[nt], acc[mt][nt]);
                acc[mt][nt] = mfma16(ah[mt], bl[nt], acc[mt][nt]);
                acc[mt][nt] = mfma16(al[mt], bh[nt], acc[mt][nt]);
            }
    }
    const float* bp = (n0 < 256) ? bk : (n0 < 512) ? (bv - 256) : (bq - 512);
#pragma unroll
    for (int mt = 0; mt < 2; mt++)
#pragma unroll
        for (int nt = 0; nt < 2; nt++)
#pragma unroll
            for (int r = 0; r < 4; r++) {
                int rg = m0 + wm * 32 + mt * 16 + q * 4 + r;
                int cg = n0 + wn * 32 + nt * 16 + m16;
                C[(size_t)rg * 768 + cg] = acc[mt][nt][r] + bp[cg];
            }
}

// FF1: inline row-mean + center + split A; relu + split out
__global__ __launch_bounds__(256) void gemm128_ff1(
    const float* __restrict__ hc, const unsigned short* __restrict__ Bbuf,
    const float* __restrict__ bias, unsigned short* __restrict__ Us)
{
    __shared__ unsigned short AsH[128 * 32];
    __shared__ unsigned short AsL[128 * 32];
    __shared__ unsigned short BsH[128 * 32];
    __shared__ unsigned short BsL[128 * 32];
    __shared__ float psum[128][2];
    __shared__ float muS[128];
    const int t = threadIdx.x;
    const int n0 = blockIdx.x * 128, m0 = blockIdx.y * 128;
    const int lane = t & 63, w = t >> 6;
    const int wm = w & 1, wn = w >> 1, m16 = lane & 15, q = lane >> 4;
    {
        int r = t >> 1, hcf = t & 1;
        const float* rp = hc + (size_t)(m0 + r) * DMODEL + hcf * 128;
        float s = 0.f;
#pragma unroll
        for (int j = 0; j < 128; j += 4) {
            float4 xv = *(const float4*)(rp + j);
            s += xv.x + xv.y + xv.z + xv.w;
        }
        psum[r][hcf] = s;
    }
    __syncthreads();
    if (t < 128) muS[t] = (psum[t][0] + psum[t][1]) * (1.0f / 256.0f);
    const f4v fz = {0.f, 0.f, 0.f, 0.f};
    f4v acc[4][4];
#pragma unroll
    for (int i = 0; i < 4; i++)
#pragma unroll
        for (int j = 0; j < 4; j++) acc[i][j] = fz;
    const int c0 = t * 2, c1 = t * 2 + 1;
    const int r0i = c0 >> 2, s0i = (c0 & 3) * 8;
    const int r1i = c1 >> 2, s1i = (c1 & 3) * 8;
    const float* ap0 = hc + (size_t)(m0 + r0i) * DMODEL + s0i;
    const float* ap1 = hc + (size_t)(m0 + r1i) * DMODEL + s1i;
    const size_t b0o = (size_t)(n0 + r0i) * 512 + s0i;
    const size_t b1o = (size_t)(n0 + r1i) * 512 + s1i;
    for (int k0 = 0; k0 < 256; k0 += 32) {
        __syncthreads();
        {
            float mu0 = muS[r0i];
            float4 a0 = *(const float4*)(ap0 + k0);
            float4 a1 = *(const float4*)(ap0 + k0 + 4);
            float v[8] = {a0.x - mu0, a0.y - mu0, a0.z - mu0, a0.w - mu0,
                          a1.x - mu0, a1.y - mu0, a1.z - mu0, a1.w - mu0};
            split8(v, &AsH[r0i * 32 + s0i], &AsL[r0i * 32 + s0i]);
        }
        {
            float mu1 = muS[r1i];
            float4 a0 = *(const float4*)(ap1 + k0);
            float4 a1 = *(const float4*)(ap1 + k0 + 4);
            float v[8] = {a0.x - mu1, a0.y - mu1, a0.z - mu1, a0.w - mu1,
                          a1.x - mu1, a1.y - mu1, a1.z - mu1, a1.w - mu1};
            split8(v, &AsH[r1i * 32 + s1i], &AsL[r1i * 32 + s1i]);
        }
        *(uint4*)&BsH[r0i * 32 + s0i] = *(const uint4*)(Bbuf + b0o + k0);
        *(uint4*)&BsH[r1i * 32 + s1i] = *(const uint4*)(Bbuf + b1o + k0);
        *(uint4*)&BsL[r0i * 32 + s0i] = *(const uint4*)(Bbuf + b0o + 256 + k0);
        *(uint4*)&BsL[r1i * 32 + s1i] = *(const uint4*)(Bbuf + b1o + 256 + k0);
        __syncthreads();
        s8v ah[4], al[4], bh[4], bl[4];
#pragma unroll
        for (int i = 0; i < 4; i++) {
            int ro = (wm * 64 + i * 16 + m16) * 32 + q * 8;
            int co = (wn * 64 + i * 16 + m16) * 32 + q * 8;
            ah[i] = *(const s8v*)&AsH[ro];
            al[i] = *(const s8v*)&AsL[ro];
            bh[i] = *(const s8v*)&BsH[co];
            bl[i] = *(const s8v*)&BsL[co];
        }
#pragma unroll
        for (int mt = 0; mt < 4; mt++)
#pragma unroll
            for (int nt = 0; nt < 4; nt++) {
                acc[mt][nt] = mfma16(ah[mt], bh[nt], acc[mt][nt]);
                acc[mt][nt] = mfma16(ah[mt], bl[nt], acc[mt][nt]);
                acc[mt][nt] = mfma16(al[mt], bh[nt], acc[mt][nt]);
            }
    }
#pragma unroll
    for (int mt = 0; mt < 4; mt++)
#pragma unroll
        for (int nt = 0; nt < 4; nt++)
#pragma unroll
            for (int r = 0; r < 4; r++) {
                int rg = m0 + wm * 64 + mt * 16 + q * 4 + r;
                int cg = n0 + wn * 64 + nt * 16 + m16;
                float val = fmaxf(acc[mt][nt][r] + bias[cg], 0.f);
                unsigned short hv = f2bf(val);
                Us[(size_t)rg * 2048 + cg] = hv;
                Us[(size_t)rg * 2048 + 1024 + cg] = f2bf(val - bf2f(hv));
            }
}

// ================= lean phi kernels (full batch: 64 bh x 16 sub) =================

__global__ __launch_bounds__(256) void phi_kv_chunk(
    const float* __restrict__ qkv, const float* __restrict__ om_l,
    const float* __restrict__ g_l, float* __restrict__ part)
{
    int bx = blockIdx.x;
    int sub = bx & 15;
    int bh = bx >> 4;                 // 0..63
    int b = bh >> 3, h = bh & 7;
    int t = threadIdx.x;
    __shared__ float omS[32][64];
    __shared__ float kS[8][32];
    __shared__ float vS[8][32];
    __shared__ float ktS[8][128];
    for (int i = t; i < 2048; i += 256) omS[i >> 6][i & 63] = om_l[(size_t)h * 2048 + i];
    float g = g_l[h];
    int e = t & 31;
    int ms = t >> 5;
    float accv[16];
#pragma unroll
    for (int i = 0; i < 16; i++) accv[i] = 0.f;
    int row0 = b * 2048 + sub * 128;
    for (int i0 = 0; i0 < 128; i0 += 8) {
        __syncthreads();
        {
            int row = row0 + i0 + ms;
            kS[ms][e] = qkv[(size_t)row * 768 + h * 32 + e];
            vS[ms][e] = qkv[(size_t)row * 768 + 256 + h * 32 + e];
        }
        __syncthreads();
        {
            int id = t * 2;
            int t2 = id >> 6;
            int mp = id & 63;
            float t_s = (float)(sub * 128 + i0 + t2) * (1.0f / 2047.0f);
#pragma unroll
            for (int u2 = 0; u2 < 2; u2++) {
                int mpp = mp + u2;
                float proj = 0.f;
#pragma unroll
                for (int d = 0; d < 32; d++) proj = fmaf(kS[t2][d], omS[d][mpp], proj);
                float slope = 2.0f - (float)mpp * 0.03125f;
                ktS[t2][mpp]      = __cosf(proj) * (INV_SQRT_M * __expf(-g * t_s * slope));
                ktS[t2][64 + mpp] = __sinf(proj) * (INV_SQRT_M * __expf(-g * (1.0f - t_s) * slope));
            }
        }
        __syncthreads();
#pragma unroll
        for (int tok = 0; tok < 8; tok++) {
            float vv = vS[tok][e];
#pragma unroll
            for (int j = 0; j < 16; j++)
                accv[j] = fmaf(ktS[tok][ms * 16 + j], vv, accv[j]);
        }
    }
    float* pp = part + (size_t)(bh * 16 + sub) * 4096;
#pragma unroll
    for (int j = 0; j < 16; j++) pp[(ms * 16 + j) * 32 + e] = accv[j];
}

// 1024 blocks (64 bh x 16 seg); independent-batch loads, fixed-order sum
__global__ __launch_bounds__(256) void kv_reduce(const float* __restrict__ part,
    float* __restrict__ kvf)
{
    int bh = blockIdx.x >> 4;
    int seg = blockIdx.x & 15;
    int i = seg * 256 + threadIdx.x;
    const float* base = part + (size_t)(bh * 16) * 4096 + i;
    float v[16];
#pragma unroll
    for (int sub = 0; sub < 16; sub++)
        v[sub] = base[(size_t)sub * 4096];
    float s = 0.f;
#pragma unroll
    for (int sub = 0; sub < 16; sub++) s += v[sub];
    kvf[(size_t)bh * 4096 + i] = s;
}

__global__ __launch_bounds__(256) void phi_o_chunk(
    const float* __restrict__ qkv, const float* __restrict__ kvf,
    const float* __restrict__ om_l, const float* __restrict__ g_l,
    unsigned short* __restrict__ osplit)
{
    int bx = blockIdx.x;
    int sub = bx & 15;
    int bh = bx >> 4;                 // 0..63
    int b = bh >> 3, h = bh & 7;
    int t = threadIdx.x;
    __shared__ float omS[32][64];
    __shared__ float kvS[128][32];
    __shared__ float qS[8][32];
    __shared__ float qtS[8][128];
    for (int i = t; i < 2048; i += 256) omS[i >> 6][i & 63] = om_l[(size_t)h * 2048 + i];
    for (int i = t; i < 4096; i += 256) kvS[i >> 5][i & 31] = kvf[(size_t)bh * 4096 + i];
    float g = g_l[h];
    int e = t & 31, tsx = t >> 5;
    int row0 = b * 2048 + sub * 128;
    for (int i0 = 0; i0 < 128; i0 += 8) {
        __syncthreads();
        qS[tsx][e] = qkv[(size_t)(row0 + i0 + tsx) * 768 + 512 + h * 32 + e];
        __syncthreads();
        {
            int id = t * 2, t2 = id >> 6, mp = id & 63;
            float t_s = (float)(sub * 128 + i0 + t2) * (1.0f / 2047.0f);
#pragma unroll
            for (int u2 = 0; u2 < 2; u2++) {
                int mpp = mp + u2;
                float proj = 0.f;
#pragma unroll
                for (int d = 0; d < 32; d++) proj = fmaf(qS[t2][d], omS[d][mpp], proj);
                float slope = 2.0f - (float)mpp * 0.03125f;
                qtS[t2][mpp]      = __cosf(proj) * (INV_SQRT_M * __expf(g * t_s * slope));
                qtS[t2][64 + mpp] = __sinf(proj) * (INV_SQRT_M * __expf(g * (1.0f - t_s) * slope));
            }
        }
        __syncthreads();
        {
            float ov = 0.f;
#pragma unroll
            for (int m = 0; m < 128; m++) ov = fmaf(qtS[tsx][m], kvS[m][e], ov);
            size_t row = (size_t)(row0 + i0 + tsx);
            unsigned short hv = f2bf(ov);
            osplit[row * 512 + h * 32 + e] = hv;
            osplit[row * 512 + 256 + h * 32 + e] = f2bf(ov - bf2f(hv));
        }
    }
}

// ================= host =================

extern "C" void kernel_launch(void* const* d_in, const int* in_sizes, int n_in,
                              void* d_out, int out_size, void* d_ws, size_t ws_size,
                              hipStream_t stream)
{
    (void)in_sizes; (void)n_in; (void)out_size; (void)ws_size;
    const float* x    = (const float*)d_in[0];
    const float* cw0  = (const float*)d_in[1];
    const float* cb0  = (const float*)d_in[2];
    const float* cw1  = (const float*)d_in[3];
    const float* cb1  = (const float*)d_in[4];
    const float* cw2  = (const float*)d_in[5];
    const float* cb2  = (const float*)d_in[6];
    const float* Wq   = (const float*)d_in[7];
    const float* bq   = (const float*)d_in[8];
    const float* Wk   = (const float*)d_in[9];
    const float* bk   = (const float*)d_in[10];
    const float* Wv   = (const float*)d_in[11];
    const float* bv   = (const float*)d_in[12];
    const float* Wo   = (const float*)d_in[13];
    const float* bo   = (const float*)d_in[14];
    const float* omega= (const float*)d_in[15];
    const float* gamma= (const float*)d_in[16];
    const float* W1   = (const float*)d_in[17];
    const float* b1   = (const float*)d_in[18];
    const float* W2   = (const float*)d_in[19];
    const float* b2   = (const float*)d_in[20];

    // ws layout — 164 MiB used (ws_size ≈ 256 MiB, measured via the harness's
    // 262144 KB poison-fill WRITE_SIZE):
    //   hc      [  0, 16M) f32
    //   qkvc    [ 16, 64M) f32 16384x768
    //   osplit  [ 64, 80M) ushort 16384x512 [hi|lo]
    //   part    [ 80, 96M) f32 64bh x 16sub x 4096
    //   kvfinal [ 96, 97M) f32 64bh x 4096
    //   wqkvt   [ 97, 98M) bf16-split k|v|q|o (4 x 131072 ushorts)
    //   w1t/w2t [ 98,100M)
    //   usp     [100,164M) ushort 16384x2048 [hi|lo]
    char* wsb = (char*)d_ws;
    float* hc     = (float*)wsb;
    float* qkvc   = (float*)(wsb + ((size_t)16 << 20));
    unsigned short* osplit = (unsigned short*)(wsb + ((size_t)64 << 20));
    float* part   = (float*)(wsb + ((size_t)80 << 20));
    float* kvfinal= (float*)(wsb + ((size_t)96 << 20));
    unsigned short* wqkvt = (unsigned short*)(wsb + ((size_t)97 << 20));
    unsigned short* wot   = wqkvt + 3 * 131072;
    unsigned short* w1t   = (unsigned short*)(wsb + ((size_t)98 << 20));
    unsigned short* w2t   = w1t + 524288;
    unsigned short* usp   = (unsigned short*)(wsb + ((size_t)100 << 20));

    // d_out: stem scratch only (h0 [0,8M), h1 [8,12M)); final output written
    // directly by layer-1 FF2.
    char* dob = (char*)d_out;
    float* h0 = (float*)dob;
    float* h1 = (float*)(dob + ((size_t)8 << 20));

    conv0_kernel<<<(BATCH * L1P + 255) / 256, 256, 0, stream>>>(x, cw0, cb0, h0);
    conv1_kernel<<<(BATCH * L2P + 255) / 256, 256, 0, stream>>>(h0, cw1, cb1, h1);
    conv2_kernel<<<BATCH * SEQ, 256, 0, stream>>>(h1, cw2, cb2, hc);

    for (int l = 0; l < 2; l++) {
        const float* Wq_l = Wq + (size_t)l * DMODEL * DMODEL;
        const float* bq_l = bq + (size_t)l * DMODEL;
        const float* Wk_l = Wk + (size_t)l * DMODEL * DMODEL;
        const float* bk_l = bk + (size_t)l * DMODEL;
        const float* Wv_l = Wv + (size_t)l * DMODEL * DMODEL;
        const float* bv_l = bv + (size_t)l * DMODEL;
        const float* Wo_l = Wo + (size_t)l * DMODEL * DMODEL;
        const float* bo_l = bo + (size_t)l * DMODEL;
        const float* om_l = omega + (size_t)l * NHEAD * DHEAD * MHALF;
        const float* g_l  = gamma + (size_t)l * NHEAD;
        const float* W1_l = W1 + (size_t)l * DMODEL * DFF;
        const float* b1_l = b1 + (size_t)l * DFF;
        const float* W2_l = W2 + (size_t)l * DFF * DMODEL;
        const float* b2_l = b2 + (size_t)l * DMODEL;

        // attention — full batch, one dispatch per stage
        tconv4_kernel<<<dim3(8, 8, 4), 256, 0, stream>>>(Wk_l, Wv_l, Wq_l, Wo_l, wqkvt);
        gemm64_qkv<<<dim3(12, BS_TOK / 64), 256, 0, stream>>>(
            hc, wqkvt, bk_l, bv_l, bq_l, qkvc);
        phi_kv_chunk<<<1024, 256, 0, stream>>>(qkvc, om_l, g_l, part);
        kv_reduce<<<1024, 256, 0, stream>>>(part, kvfinal);
        phi_o_chunk<<<1024, 256, 0, stream>>>(qkvc, kvfinal, om_l, g_l, osplit);
        gemm64s<true><<<dim3(4, BS_TOK / 64), 256, 0, stream>>>(
            osplit, 512, 256, wot, 512, 256, bo_l, hc, hc, DMODEL, DMODEL);

        // FF — full batch
        tconv_ff_kernel<<<dim3(32, 8, 2), 256, 0, stream>>>(W1_l, W2_l, w1t, w2t);
        gemm128_ff1<<<dim3(DFF / 128, BS_TOK / 128), 256, 0, stream>>>(
            hc, w1t, b1_l, usp);
        float* dest = (l == 1) ? (float*)d_out : hc;
        gemm64s<true><<<dim3(4, BS_TOK / 64), 256, 0, stream>>>(
            usp, 2048, 1024, w2t, 2048, 1024, b2_l, hc, dest, DMODEL, DFF);
    }
}